// Round 1
// baseline (237.839 us; speedup 1.0000x reference)
//
#include <hip/hip_runtime.h>
#include <cstdint>
#include <cstddef>

typedef unsigned short u16;
typedef __bf16 bf16x8 __attribute__((ext_vector_type(8)));
typedef float f32x4 __attribute__((ext_vector_type(4)));

#define DEVI __device__ __forceinline__

DEVI u16 f2bf(float f){
  union { float f; unsigned u; } v; v.f = f;
  unsigned r = v.u + 0x7fffu + ((v.u >> 16) & 1u);
  return (u16)(r >> 16);
}

#if defined(__has_builtin)
#if __has_builtin(__builtin_amdgcn_exp2f)
#define EXP2F(x) __builtin_amdgcn_exp2f(x)
#else
#define EXP2F(x) exp2f(x)
#endif
#else
#define EXP2F(x) exp2f(x)
#endif

#define MFMA16(a,b,c) __builtin_amdgcn_mfma_f32_16x16x32_bf16((a),(b),(c),0,0,0)

// ---------------------------------------------------------------------------
// Workspace layout (bytes)
//  Xb  : bf16 [3][8192][512]          @ 0         (25165824)
//  Wt  : bf16 [4][512][512] (n-major) @ 25165824  (2097152)
//  Qb  : bf16 [32][2048][64]          @ 27262976  (8388608)   (pre-scaled 1/8)
//  Kb  : bf16 [32][2048][64]          @ 35651584  (8388608)
//  Vb  : bf16 [32][2048][64]          @ 44040192  (8388608)
//  Vt  : bf16 [32][64][2048]          @ 52428800  (8388608)
//  CTX : bf16 [8192][512]             @ 60817408  (8388608)
//  total 69206016 bytes (~66 MB)
// ---------------------------------------------------------------------------

// Convert the three f32 activation inputs to bf16, contiguous.
__global__ void k_prep_x(const float* __restrict__ q, const float* __restrict__ k,
                         const float* __restrict__ v, u16* __restrict__ xb){
  size_t t = (size_t)blockIdx.x*blockDim.x + threadIdx.x;
  size_t base = t*8;                       // 12582912 elements total, exact fit
  const float* s;
  if (base < 4194304u)      s = q + base;
  else if (base < 8388608u) s = k + (base - 4194304u);
  else                      s = v + (base - 8388608u);
  float4 a = *(const float4*)s;
  float4 b = *(const float4*)(s+4);
  ushort4 o0, o1;
  o0.x=f2bf(a.x); o0.y=f2bf(a.y); o0.z=f2bf(a.z); o0.w=f2bf(a.w);
  o1.x=f2bf(b.x); o1.y=f2bf(b.y); o1.z=f2bf(b.z); o1.w=f2bf(b.w);
  *(ushort4*)(xb + base)     = o0;
  *(ushort4*)(xb + base + 4) = o1;
}

// Transpose 4 weight matrices f32 [k][n] -> bf16 [n][k] (K-major for MFMA B).
__global__ void k_prep_w(const float* __restrict__ w0, const float* __restrict__ w1,
                         const float* __restrict__ w2, const float* __restrict__ w3,
                         u16* __restrict__ wt){
  __shared__ u16 tile[64][72];
  int p = blockIdx.z;
  const float* W = (p==0)?w0:((p==1)?w1:((p==2)?w2:w3));
  int k0 = blockIdx.x*64, n0 = blockIdx.y*64;
  int t = threadIdx.x;
  int tr = t >> 4, tc = t & 15;
  #pragma unroll
  for (int pass=0; pass<4; pass++){
    int row = pass*16 + tr;                           // k_local
    float4 a = *(const float4*)(W + (size_t)(k0+row)*512 + n0 + tc*4);
    tile[row][tc*4+0] = f2bf(a.x);
    tile[row][tc*4+1] = f2bf(a.y);
    tile[row][tc*4+2] = f2bf(a.z);
    tile[row][tc*4+3] = f2bf(a.w);
  }
  __syncthreads();
  #pragma unroll
  for (int pass=0; pass<4; pass++){
    int n = pass*16 + tr;                             // n_local
    ushort4 o;
    o.x = tile[tc*4+0][n];
    o.y = tile[tc*4+1][n];
    o.z = tile[tc*4+2][n];
    o.w = tile[tc*4+3][n];
    *(ushort4*)(wt + (size_t)p*262144 + (size_t)(n0+n)*512 + k0 + tc*4) = o;
  }
}

// QKV projection: out = X @ W + bias; Q additionally scaled by 0.125.
// Output layout [b][h][s][64] bf16. Grid (64, 4, 3), block 256.
__global__ __launch_bounds__(256)
void k_gemm_qkv(const u16* __restrict__ xb, const u16* __restrict__ wt,
                const float* __restrict__ bq, const float* __restrict__ bk,
                const float* __restrict__ bv,
                u16* __restrict__ qb, u16* __restrict__ kb, u16* __restrict__ vb){
  int p = blockIdx.z;
  const u16* A  = xb + (size_t)p*4194304;
  const u16* Bt = wt + (size_t)p*262144;
  const float* bias = (p==0)?bq:((p==1)?bk:bv);
  u16* outp = (p==0)?qb:((p==1)?kb:vb);
  float osc = (p==0)?0.125f:1.0f;
  int l = threadIdx.x & 63, w = threadIdx.x >> 6;
  int lr = l & 15, lg = l >> 4;
  int m0 = blockIdx.x*128 + (w>>1)*64;
  int n0 = blockIdx.y*128 + (w&1)*64;
  f32x4 acc[4][4] = {};
  for (int k0=0; k0<512; k0+=32){
    bf16x8 af[4], bfr[4];
    #pragma unroll
    for (int i=0;i<4;i++) af[i]  = *(const bf16x8*)(A  + (size_t)(m0+i*16+lr)*512 + k0 + lg*8);
    #pragma unroll
    for (int j=0;j<4;j++) bfr[j] = *(const bf16x8*)(Bt + (size_t)(n0+j*16+lr)*512 + k0 + lg*8);
    #pragma unroll
    for (int i=0;i<4;i++)
      #pragma unroll
      for (int j=0;j<4;j++)
        acc[i][j] = MFMA16(af[i], bfr[j], acc[i][j]);
  }
  #pragma unroll
  for (int i=0;i<4;i++){
    #pragma unroll
    for (int j=0;j<4;j++){
      int n = n0 + j*16 + lr;
      int h = n >> 6, d = n & 63;
      float bb = bias[n];
      #pragma unroll
      for (int rg=0;rg<4;rg++){
        int m = m0 + i*16 + 4*lg + rg;
        int b = m >> 11, s = m & 2047;
        float val = (acc[i][j][rg] + bb)*osc;
        outp[(((size_t)b*8 + h)*2048 + s)*64 + d] = f2bf(val);
      }
    }
  }
}

// Transpose V: [bh][2048][64] -> [bh][64][2048] so PV B-operand is kv-contiguous.
__global__ void k_vt(const u16* __restrict__ vb, u16* __restrict__ vt){
  __shared__ u16 tile[64][72];
  int bh = blockIdx.z;
  int s0 = blockIdx.x*64;
  int t = threadIdx.x;
  int tr = t>>4, tc = t&15;
  const u16* src = vb + ((size_t)bh*2048 + s0)*64;
  #pragma unroll
  for (int pass=0; pass<4; pass++){
    int row = pass*16 + tr;                           // s_local
    ushort4 a = *(const ushort4*)(src + (size_t)row*64 + tc*4);
    tile[row][tc*4+0]=a.x; tile[row][tc*4+1]=a.y;
    tile[row][tc*4+2]=a.z; tile[row][tc*4+3]=a.w;
  }
  __syncthreads();
  u16* dst = vt + (size_t)bh*64*2048;
  #pragma unroll
  for (int pass=0; pass<4; pass++){
    int d = pass*16 + tr;
    ushort4 o;
    o.x = tile[tc*4+0][d]; o.y = tile[tc*4+1][d];
    o.z = tile[tc*4+2][d]; o.w = tile[tc*4+3][d];
    *(ushort4*)(dst + (size_t)d*2048 + s0 + tc*4) = o;
  }
}

// Flash attention. Grid (16,1,32), block 256 (4 waves x 32 q-rows).
// Swapped QK^T (mfma(K,Q) -> S^T) so softmax row-reduce is register-local +
// shfl_xor(16,32). P re-shaped via per-wave XOR-swizzled LDS (wave-local sync).
__global__ __launch_bounds__(256)
void k_attn(const u16* __restrict__ qbuf, const u16* __restrict__ kbuf,
            const u16* __restrict__ vtb, u16* __restrict__ ctx){
  int l = threadIdx.x & 63, w = threadIdx.x >> 6;
  int lr = l & 15, lg = l >> 4;
  int bh = blockIdx.z; int b = bh >> 3, h = bh & 7;
  int q0 = blockIdx.x*128 + w*32;

  const u16* Qp = qbuf + ((size_t)bh*2048 + q0)*64;
  const u16* Kp = kbuf + (size_t)bh*2048*64;
  const u16* Vp = vtb  + (size_t)bh*64*2048;

  __shared__ __align__(16) u16   P_lds[4*2048];   // 4 waves x 32x64 bf16 (4KB each)
  __shared__ __align__(16) float sc_lds[4][32];
  u16*   Pw  = &P_lds[w*2048];
  float* scw = sc_lds[w];

  bf16x8 qf[2][2];
  #pragma unroll
  for (int j=0;j<2;j++)
    #pragma unroll
    for (int kk=0;kk<2;kk++)
      qf[j][kk] = *(const bf16x8*)(Qp + (size_t)(j*16+lr)*64 + kk*32 + lg*8);

  f32x4 oacc[2][4] = {};
  float m_run[2] = {-1e30f, -1e30f};
  float l_run[2] = {0.f, 0.f};
  const float L2E = 1.44269504088896340736f;

  for (int kv0 = 0; kv0 < 2048; kv0 += 64){
    // --- S^T = K * Q^T  (rows = kv, cols = q) ---
    f32x4 sacc[4][2] = {};
    #pragma unroll
    for (int kk=0;kk<2;kk++){
      bf16x8 kf[4];
      #pragma unroll
      for (int i=0;i<4;i++)
        kf[i] = *(const bf16x8*)(Kp + (size_t)(kv0 + i*16 + lr)*64 + kk*32 + lg*8);
      #pragma unroll
      for (int i=0;i<4;i++)
        #pragma unroll
        for (int j=0;j<2;j++)
          sacc[i][j] = MFMA16(kf[i], qf[j][kk], sacc[i][j]);
    }
    // WAR guard: previous tile's P/scale reads must be complete before rewrite.
    asm volatile("s_waitcnt lgkmcnt(0)" ::: "memory");
    // --- online softmax (per lane: q = lr + 16j) ---
    #pragma unroll
    for (int j=0;j<2;j++){
      float pm = -1e30f;
      #pragma unroll
      for (int i=0;i<4;i++)
        #pragma unroll
        for (int rg=0;rg<4;rg++)
          pm = fmaxf(pm, sacc[i][j][rg]);
      pm = fmaxf(pm, __shfl_xor(pm, 16));
      pm = fmaxf(pm, __shfl_xor(pm, 32));
      float mn  = fmaxf(m_run[j], pm);
      float fr  = EXP2F((m_run[j] - mn)*L2E);
      float mnl = mn * L2E;
      float psum = 0.f;
      int qrow = lr + 16*j;
      #pragma unroll
      for (int i=0;i<4;i++){
        ushort4 pk;
        #pragma unroll
        for (int rg=0;rg<4;rg++){
          float pv = EXP2F(sacc[i][j][rg]*L2E - mnl);
          psum += pv;
          ((u16*)&pk)[rg] = f2bf(pv);
        }
        int o    = 8*lg + 32*i;                       // byte offset along kv
        int slot = (o >> 4) ^ (qrow & 7);
        int addr = qrow*128 + (slot<<4) + (o & 15);
        *(ushort4*)((char*)Pw + addr) = pk;
      }
      psum += __shfl_xor(psum, 16);
      psum += __shfl_xor(psum, 32);
      l_run[j] = l_run[j]*fr + psum;
      m_run[j] = mn;
      scw[qrow] = fr;
    }
    asm volatile("s_waitcnt lgkmcnt(0)" ::: "memory");
    // --- rescale O by exp(m_old - m_new), broadcast via LDS ---
    #pragma unroll
    for (int fi=0;fi<2;fi++){
      f32x4 fv = *(const f32x4*)&scw[4*lg + 16*fi];
      #pragma unroll
      for (int fj=0;fj<4;fj++)
        #pragma unroll
        for (int rg=0;rg<4;rg++)
          oacc[fi][fj][rg] *= fv[rg];
    }
    // --- O += P * V ---
    #pragma unroll
    for (int kk=0;kk<2;kk++){
      bf16x8 pf[2];
      #pragma unroll
      for (int fi=0;fi<2;fi++){
        int qrow = fi*16 + lr;
        int slot = (kk*4 + lg) ^ (qrow & 7);
        pf[fi] = *(const bf16x8*)((char*)Pw + qrow*128 + (slot<<4));
      }
      bf16x8 vf[4];
      #pragma unroll
      for (int fj=0;fj<4;fj++)
        vf[fj] = *(const bf16x8*)(Vp + (size_t)(fj*16+lr)*2048 + kv0 + kk*32 + lg*8);
      #pragma unroll
      for (int fi=0;fi<2;fi++)
        #pragma unroll
        for (int fj=0;fj<4;fj++)
          oacc[fi][fj] = MFMA16(pf[fi], vf[fj], oacc[fi][fj]);
    }
  }
  // --- finalize: O /= l_run, store to CTX [m][512] bf16 ---
  asm volatile("s_waitcnt lgkmcnt(0)" ::: "memory");
  scw[lr]      = 1.f / l_run[0];
  scw[lr + 16] = 1.f / l_run[1];
  asm volatile("s_waitcnt lgkmcnt(0)" ::: "memory");
  #pragma unroll
  for (int fi=0;fi<2;fi++){
    f32x4 fv = *(const f32x4*)&scw[4*lg + 16*fi];
    #pragma unroll
    for (int fj=0;fj<4;fj++){
      int col = h*64 + fj*16 + lr;
      #pragma unroll
      for (int rg=0;rg<4;rg++){
        int qg = q0 + fi*16 + 4*lg + rg;
        float v = oacc[fi][fj][rg]*fv[rg];
        ctx[((size_t)(b*2048 + qg))*512 + col] = f2bf(v);
      }
    }
  }
}

// Output projection + bias + residual + LayerNorm, fused.
// BM=32 rows/block, 8 waves each own a 64-col strip. Grid 256, block 512.
__global__ __launch_bounds__(512)
void k_outln(const u16* __restrict__ ctx, const u16* __restrict__ wto,
             const float* __restrict__ bo, const float* __restrict__ resid,
             const float* __restrict__ g, const float* __restrict__ beta,
             float* __restrict__ out){
  int l = threadIdx.x & 63, w = threadIdx.x >> 6;
  int lr = l & 15, lg = l >> 4;
  int m0 = blockIdx.x * 32;
  int nc0 = w * 64;
  f32x4 acc[2][4] = {};
  for (int k0=0;k0<512;k0+=32){
    bf16x8 af[2], bfr[4];
    #pragma unroll
    for (int i=0;i<2;i++) af[i]  = *(const bf16x8*)(ctx + (size_t)(m0+i*16+lr)*512 + k0 + lg*8);
    #pragma unroll
    for (int j=0;j<4;j++) bfr[j] = *(const bf16x8*)(wto + (size_t)(nc0+j*16+lr)*512 + k0 + lg*8);
    #pragma unroll
    for (int i=0;i<2;i++)
      #pragma unroll
      for (int j=0;j<4;j++)
        acc[i][j] = MFMA16(af[i], bfr[j], acc[i][j]);
  }
  float s1[2][4] = {}, s2[2][4] = {};
  #pragma unroll
  for (int i=0;i<2;i++)
    #pragma unroll
    for (int j=0;j<4;j++){
      int col = nc0 + j*16 + lr;
      float bb = bo[col];
      #pragma unroll
      for (int rg=0;rg<4;rg++){
        int m = m0 + i*16 + 4*lg + rg;
        float v = acc[i][j][rg] + bb + resid[(size_t)m*512 + col];
        acc[i][j][rg] = v;
        s1[i][rg] += v;
        s2[i][rg] += v*v;
      }
    }
  #pragma unroll
  for (int i=0;i<2;i++)
    #pragma unroll
    for (int rg=0;rg<4;rg++){
      #pragma unroll
      for (int mk=1; mk<16; mk<<=1){
        s1[i][rg] += __shfl_xor(s1[i][rg], mk);
        s2[i][rg] += __shfl_xor(s2[i][rg], mk);
      }
    }
  __shared__ float red1[32][8], red2[32][8];
  if (lr == 0){
    #pragma unroll
    for (int i=0;i<2;i++)
      #pragma unroll
      for (int rg=0;rg<4;rg++){
        int row = i*16 + 4*lg + rg;
        red1[row][w] = s1[i][rg];
        red2[row][w] = s2[i][rg];
      }
  }
  __syncthreads();
  #pragma unroll
  for (int i=0;i<2;i++)
    #pragma unroll
    for (int rg=0;rg<4;rg++){
      int row = i*16 + 4*lg + rg;
      float t1 = 0.f, t2 = 0.f;
      #pragma unroll
      for (int ww=0; ww<8; ww++){ t1 += red1[row][ww]; t2 += red2[row][ww]; }
      float mu   = t1 * (1.f/512.f);
      float var  = t2 * (1.f/512.f) - mu*mu;
      float rstd = rsqrtf(var + 1e-5f);
      int m = m0 + row;
      #pragma unroll
      for (int j=0;j<4;j++){
        int col = nc0 + j*16 + lr;
        out[(size_t)m*512 + col] = (acc[i][j][rg] - mu)*rstd*g[col] + beta[col];
      }
    }
}

extern "C" void kernel_launch(void* const* d_in, const int* in_sizes, int n_in,
                              void* d_out, int out_size, void* d_ws, size_t ws_size,
                              hipStream_t stream){
  const float* q   = (const float*)d_in[0];
  const float* k   = (const float*)d_in[1];
  const float* v   = (const float*)d_in[2];
  const float* wq  = (const float*)d_in[3];
  const float* bq  = (const float*)d_in[4];
  const float* wk  = (const float*)d_in[5];
  const float* bk  = (const float*)d_in[6];
  const float* wv  = (const float*)d_in[7];
  const float* bv  = (const float*)d_in[8];
  const float* wo  = (const float*)d_in[9];
  const float* bo  = (const float*)d_in[10];
  const float* lng = (const float*)d_in[11];
  const float* lnb = (const float*)d_in[12];
  float* out = (float*)d_out;
  char* ws = (char*)d_ws;
  u16* xb  = (u16*)(ws + 0);
  u16* wt  = (u16*)(ws + 25165824);
  u16* qb  = (u16*)(ws + 27262976);
  u16* kb  = (u16*)(ws + 35651584);
  u16* vb  = (u16*)(ws + 44040192);
  u16* vt  = (u16*)(ws + 52428800);
  u16* ctx = (u16*)(ws + 60817408);

  k_prep_x<<<6144, 256, 0, stream>>>(q, k, v, xb);
  k_prep_w<<<dim3(8,8,4), 256, 0, stream>>>(wq, wk, wv, wo, wt);
  k_gemm_qkv<<<dim3(64,4,3), 256, 0, stream>>>(xb, wt, bq, bk, bv, qb, kb, vb);
  k_vt<<<dim3(32,1,32), 256, 0, stream>>>(vb, vt);
  k_attn<<<dim3(16,1,32), 256, 0, stream>>>(qb, kb, vt, ctx);
  k_outln<<<256, 512, 0, stream>>>(ctx, wt + 3*262144, bo, q, lng, lnb, out);
}